// Round 5
// baseline (279.635 us; speedup 1.0000x reference)
//
#include <hip/hip_runtime.h>

// Problem constants
#define B_ 8
#define N_ 2048
#define T_ 12
#define F_ 64
#define NT 24576    // N_*T_
#define CH 192      // 3 * 64 output channels
#define C_ 768      // 64 * 12 rows per diffusion GEMM B-operand

typedef __bf16 bf16x8 __attribute__((ext_vector_type(8)));
typedef float f32x4 __attribute__((ext_vector_type(4)));

typedef const __attribute__((address_space(1))) unsigned int as1_uint;
typedef __attribute__((address_space(3))) unsigned int as3_uint;

__device__ __forceinline__ void gload16(const void* g, void* l) {
  __builtin_amdgcn_global_load_lds((as1_uint*)g, (as3_uint*)l, 16, 0, 0);
}

__device__ __forceinline__ unsigned short f2bf(float f) {
  unsigned int u = __float_as_uint(f);
  u += 0x7FFFu + ((u >> 16) & 1u);   // RNE
  return (unsigned short)(u >> 16);
}

__device__ __forceinline__ float leaky(float v) {
  return v >= 0.0f ? v : 0.01f * v;
}

// ---------------------------------------------------------------------------
// adj fp32 -> bf16
// ---------------------------------------------------------------------------
__global__ __launch_bounds__(256) void convert_adj_k(const float* __restrict__ adj,
                                                     unsigned short* __restrict__ adjb) {
  size_t i = (size_t)blockIdx.x * 256 + threadIdx.x;
  const float4 v = reinterpret_cast<const float4*>(adj)[i];
  ushort4 u;
  u.x = f2bf(v.x); u.y = f2bf(v.y); u.z = f2bf(v.z); u.w = f2bf(v.w);
  reinterpret_cast<ushort4*>(adjb)[i] = u;
}

// ---------------------------------------------------------------------------
// Stage W^T (bf16, padded rows of 72) + bias into LDS. W is [64 f][64 o].
// ---------------------------------------------------------------------------
__device__ __forceinline__ void stage_wt(const float* __restrict__ W,
                                         unsigned short* Wt, int tid) {
  const int f = tid >> 2;
  const int q = tid & 3;
  const float4* row = reinterpret_cast<const float4*>(W + f * 64 + q * 16);
#pragma unroll
  for (int v4 = 0; v4 < 4; ++v4) {
    float4 v = row[v4];
    const int ob = q * 16 + v4 * 4;
    Wt[(ob + 0) * 72 + f] = f2bf(v.x);
    Wt[(ob + 1) * 72 + f] = f2bf(v.y);
    Wt[(ob + 2) * 72 + f] = f2bf(v.z);
    Wt[(ob + 3) * 72 + f] = f2bf(v.w);
  }
}

// ---------------------------------------------------------------------------
// p0_k: out[:, 0:64] = leaky(x . W0 + b0)   via MFMA, linear-e mapping.
// ---------------------------------------------------------------------------
__global__ __launch_bounds__(256) void p0_k(const float* __restrict__ x,
                                            const float* __restrict__ W0,
                                            const float* __restrict__ bia0,
                                            float* __restrict__ out) {
  __shared__ unsigned short Wt[64 * 72];
  __shared__ float bias[64];
  const int tid = threadIdx.x;
  stage_wt(W0, Wt, tid);
  if (tid < 64) bias[tid] = bia0[tid];
  __syncthreads();

  const int lane = tid & 63;
  const int wave = tid >> 6;
  const int b = blockIdx.y;
  const int e = blockIdx.x * 64 + wave * 16 + (lane & 15);
  const int fgrp = (lane >> 4) * 8;
  const float* xb = x + (size_t)b * F_ * NT;

  bf16x8 xf[2];
#pragma unroll
  for (int kf = 0; kf < 2; ++kf)
#pragma unroll
    for (int j = 0; j < 8; ++j)
      xf[kf][j] = (__bf16)xb[(size_t)(fgrp + kf * 32 + j) * NT + e];

  float* outb = out + (size_t)b * CH * NT;
#pragma unroll
  for (int ob = 0; ob < 4; ++ob) {
    f32x4 acc = {};
#pragma unroll
    for (int kf = 0; kf < 2; ++kf) {
      bf16x8 af = *reinterpret_cast<const bf16x8*>(
          &Wt[(ob * 16 + (lane & 15)) * 72 + kf * 32 + fgrp]);
      acc = __builtin_amdgcn_mfma_f32_16x16x32_bf16(af, xf[kf], acc, 0, 0, 0);
    }
#pragma unroll
    for (int r = 0; r < 4; ++r) {
      const int o = ob * 16 + (lane >> 4) * 4 + r;
      outb[(size_t)o * NT + e] = leaky(acc[r] + bias[o]);
    }
  }
}

// ---------------------------------------------------------------------------
// p12_k: G1 = x.W1 + b1, G2 = x.W2 + b2 (no activation), bf16 to
// G_p[(o*12+t)*N_ + n]  (K-contig for GEMM).
// ---------------------------------------------------------------------------
__global__ __launch_bounds__(256) void p12_k(const float* __restrict__ x,
                                             const float* __restrict__ W1,
                                             const float* __restrict__ bia1,
                                             const float* __restrict__ W2,
                                             const float* __restrict__ bia2,
                                             unsigned short* __restrict__ G1,
                                             unsigned short* __restrict__ G2) {
  __shared__ unsigned short Wt[2][64 * 72];
  __shared__ float bias[2][64];
  const int tid = threadIdx.x;
  stage_wt(W1, Wt[0], tid);
  stage_wt(W2, Wt[1], tid);
  if (tid < 64) bias[0][tid] = bia1[tid];
  else if (tid < 128) bias[1][tid - 64] = bia2[tid - 64];
  __syncthreads();

  const int lane = tid & 63;
  const int wave = tid >> 6;
  const int b = blockIdx.y;
  const int n = blockIdx.x * 16 + (lane & 15);
  const int fgrp = (lane >> 4) * 8;
  const float* xb = x + (size_t)b * F_ * NT;
  unsigned short* Gp[2] = {G1 + (size_t)b * C_ * N_, G2 + (size_t)b * C_ * N_};

#pragma unroll
  for (int it = 0; it < 3; ++it) {
    const int t = wave * 3 + it;
    const int e = n * T_ + t;

    bf16x8 xf[2];
#pragma unroll
    for (int kf = 0; kf < 2; ++kf)
#pragma unroll
      for (int j = 0; j < 8; ++j)
        xf[kf][j] = (__bf16)xb[(size_t)(fgrp + kf * 32 + j) * NT + e];

#pragma unroll
    for (int p = 0; p < 2; ++p) {
#pragma unroll
      for (int ob = 0; ob < 4; ++ob) {
        f32x4 acc = {};
#pragma unroll
        for (int kf = 0; kf < 2; ++kf) {
          bf16x8 af = *reinterpret_cast<const bf16x8*>(
              &Wt[p][(ob * 16 + (lane & 15)) * 72 + kf * 32 + fgrp]);
          acc = __builtin_amdgcn_mfma_f32_16x16x32_bf16(af, xf[kf], acc, 0, 0, 0);
        }
#pragma unroll
        for (int r = 0; r < 4; ++r) {
          const int o = ob * 16 + (lane >> 4) * 4 + r;
          Gp[p][(size_t)(o * T_ + t) * N_ + n] = f2bf(acc[r] + bias[p][o]);
        }
      }
    }
  }
}

// ---------------------------------------------------------------------------
// 256x192 diffusion GEMM, 2 phases per K-tile, 24 MFMA per phase.
// C[n][c] = sum_m adj[b][n][m] * Bt[b][c][m],  K = 2048, BK = 64 (2 kh of 32).
// 512 threads = 8 waves (2 M x 4 N), per-wave output 128x48, acc[8][3].
//
// Phase p (p = kt*2 + kh) computes plane p and stages plane p+3 (A+B of one
// kh-half, 4 gloads), then uniform s_waitcnt vmcnt(8): the plane needed NEXT
// phase drains one phase early, >=2 barriers before its ds_read. Each LDS
// plane overwritten in the phase after its last read (barrier-separated).
//
// LDS 128KB, planes [2 kh][256 rows][32 shorts]. Conflict-free via granule
// XOR: LDS(r,c) holds global(r, c ^ ((r>>1)&3)); staging pre-swizzles the
// per-lane GLOBAL source col (linear gload_lds dest), reads bake the XOR into
// the lane constant kg.  B rows 192..255 staged-but-unused (source clamped)
// so all waves issue identical load counts (vmcnt-uniform).
// grid 256 = 8 batches x (8 n-tiles x 4 c-tiles); blockIdx&7 = batch = XCD.
// ---------------------------------------------------------------------------
__global__ __launch_bounds__(512, 2) void gemm8_k(
    const unsigned short* __restrict__ adjb,
    const unsigned short* __restrict__ Bt,
    float* __restrict__ out,
    unsigned short* __restrict__ Ht,
    const int mode, const int ochan_base)
{
  extern __shared__ __align__(16) unsigned short lds[];  // 65536 shorts = 128KB
  // layout (shorts): A buf0 @0, A buf1 @16384, B buf0 @32768, B buf1 @49152
  // within buf: kh*8192 + row*32 + col

  const int tid  = threadIdx.x;
  const int lane = tid & 63;
  const int wave = tid >> 6;
  const int wr = wave >> 2;      // 0..1  (M half, 128 rows)
  const int wc = wave & 3;       // 0..3  (N quarter, 48 cols)

  const int b  = blockIdx.x & 7;            // batch == XCD (round-robin)
  const int w  = blockIdx.x >> 3;           // 0..31
  const int n0 = (w & 7) * 256;
  const int c0 = (w >> 3) * 192;

  const unsigned short* A  = adjb + (size_t)b * N_ * N_;
  const unsigned short* Bm = Bt   + (size_t)b * C_ * N_;

  // staging: lane covers row (wave*16 + lane>>2) [+128 for 2nd gload],
  // source col granule pre-swizzled.
  const int swzSrc = ((lane & 3) ^ ((lane >> 3) & 3)) * 8;   // shorts
  const unsigned short* aSt1 = A + (size_t)(n0 + wave * 16 + (lane >> 2)) * N_ + swzSrc;
  const unsigned short* aSt2 = aSt1 + (size_t)128 * N_;
  const unsigned short* bSt1 = Bm + (size_t)(c0 + wave * 16 + (lane >> 2)) * N_ + swzSrc;
  const int brow2 = c0 + 128 + wave * 16 + (lane >> 2);
  const unsigned short* bSt2 = Bm + (size_t)(brow2 < C_ ? brow2 : C_ - 1) * N_ + swzSrc;
  const int ldsW = wave * 512;   // shorts: wave's 16-row stripe within plane

  // fragment read bases (shorts), swizzled k-granule
  const int kg  = (lane >> 4) ^ ((lane >> 1) & 3);
  const int aRd = (wr * 128 + (lane & 15)) * 32 + kg * 8;
  const int bRd = (wc * 48  + (lane & 15)) * 32 + kg * 8;

  f32x4 acc[8][3] = {};
  bf16x8 afr[8], bfr[3];

#define STGA(LDSB, KT, KH) \
  gload16(aSt1 + (KT) * 64 + (KH) * 32, lds + (LDSB) + (KH) * 8192 + ldsW); \
  gload16(aSt2 + (KT) * 64 + (KH) * 32, lds + (LDSB) + (KH) * 8192 + ldsW + 4096);

#define STGB(LDSB, KT, KH) \
  gload16(bSt1 + (KT) * 64 + (KH) * 32, lds + (LDSB) + (KH) * 8192 + ldsW); \
  gload16(bSt2 + (KT) * 64 + (KH) * 32, lds + (LDSB) + (KH) * 8192 + ldsW + 4096);

#define RD_B(BUFB, KH) { \
  _Pragma("unroll") \
  for (int nf = 0; nf < 3; ++nf) \
    bfr[nf] = *(const bf16x8*)(lds + (BUFB) + (KH) * 8192 + nf * 512 + bRd); }

#define RD_A8(BUFA, KH) { \
  _Pragma("unroll") \
  for (int mm = 0; mm < 8; ++mm) \
    afr[mm] = *(const bf16x8*)(lds + (BUFA) + (KH) * 8192 + mm * 512 + aRd); }

#define MFMA24() { \
  _Pragma("unroll") \
  for (int mm = 0; mm < 8; ++mm) \
  _Pragma("unroll") \
  for (int nf = 0; nf < 3; ++nf) \
    acc[mm][nf] = __builtin_amdgcn_mfma_f32_16x16x32_bf16( \
        afr[mm], bfr[nf], acc[mm][nf], 0, 0, 0); }

#define MIDBAR() \
  __builtin_amdgcn_s_barrier(); \
  asm volatile("s_waitcnt lgkmcnt(0)" ::: "memory"); \
  __builtin_amdgcn_sched_barrier(0); \
  __builtin_amdgcn_s_setprio(1);

#define ENDBAR() \
  __builtin_amdgcn_s_setprio(0); \
  __builtin_amdgcn_s_barrier();

#define WAITV(N) asm volatile("s_waitcnt vmcnt(" #N ")" ::: "memory");

  // ---- prologue: stage (0)kh0 A,B ; (0)kh1 A,B ; (1)kh0 A,B  (12 loads)
  STGA(0, 0, 0)      STGB(32768, 0, 0)
  STGA(0, 0, 1)      STGB(32768, 0, 1)
  STGA(16384, 1, 0)  STGB(49152, 1, 0)
  WAITV(8)                       // (0)kh0 A+B landed
  __builtin_amdgcn_s_barrier();

  // ---- main loop: pairs i = 0..14 (K-tiles 0..29); 4 phases per pair
#pragma unroll 1
  for (int it = 0; it < 15; ++it) {
    const int kt0 = 2 * it;
    // ph0: compute (kt0, kh0) in buf0 ; stage (kt0+1)kh1 -> buf1
    RD_B(32768, 0) RD_A8(0, 0)
    STGA(16384, kt0 + 1, 1) STGB(49152, kt0 + 1, 1)
    WAITV(8)
    MIDBAR() MFMA24() ENDBAR()
    // ph1: compute (kt0, kh1) in buf0 ; stage (kt0+2)kh0 -> buf0
    RD_B(32768, 1) RD_A8(0, 1)
    STGA(0, kt0 + 2, 0) STGB(32768, kt0 + 2, 0)
    WAITV(8)
    MIDBAR() MFMA24() ENDBAR()
    // ph2: compute (kt0+1, kh0) in buf1 ; stage (kt0+2)kh1 -> buf0
    RD_B(49152, 0) RD_A8(16384, 0)
    STGA(0, kt0 + 2, 1) STGB(32768, kt0 + 2, 1)
    WAITV(8)
    MIDBAR() MFMA24() ENDBAR()
    // ph3: compute (kt0+1, kh1) in buf1 ; stage (kt0+3)kh0 -> buf1
    RD_B(49152, 1) RD_A8(16384, 1)
    STGA(16384, kt0 + 3, 0) STGB(49152, kt0 + 3, 0)
    WAITV(8)
    MIDBAR() MFMA24() ENDBAR()
  }

  // ---- tail pair (K-tiles 30, 31): only (31)kh1 still to stage
  {
    // ph0: compute (30)kh0 ; stage (31)kh1 -> buf1
    RD_B(32768, 0) RD_A8(0, 0)
    STGA(16384, 31, 1) STGB(49152, 31, 1)
    WAITV(8)
    MIDBAR() MFMA24() ENDBAR()
    // ph1: compute (30)kh1 ; drain (31)kh0
    RD_B(32768, 1) RD_A8(0, 1)
    WAITV(4)
    MIDBAR() MFMA24() ENDBAR()
    // ph2: compute (31)kh0 ; drain (31)kh1
    RD_B(49152, 0) RD_A8(16384, 0)
    WAITV(0)
    MIDBAR() MFMA24() ENDBAR()
    // ph3: compute (31)kh1
    RD_B(49152, 1) RD_A8(16384, 1)
    MIDBAR() MFMA24() ENDBAR()
  }

  // ---- epilogue. D frag: col(c) = lane&15, row(n) = (lane>>4)*4 + reg
  const int r4 = (lane >> 4) * 4;
  if (mode == 0) {
    float* outb = out + (size_t)b * CH * NT;
#pragma unroll
    for (int m = 0; m < 8; ++m) {
#pragma unroll
      for (int nf = 0; nf < 3; ++nf) {
        const int c = c0 + wc * 48 + nf * 16 + (lane & 15);
        const int o = c / 12;
        const int t = c - o * 12;
#pragma unroll
        for (int r = 0; r < 4; ++r) {
          const int n = n0 + wr * 128 + m * 16 + r4 + r;
          outb[((size_t)(ochan_base + o) * N_ + n) * T_ + t] = leaky(acc[m][nf][r]);
        }
      }
    }
  } else {
    unsigned short* Hb = Ht + (size_t)b * C_ * N_;
#pragma unroll
    for (int m = 0; m < 8; ++m) {
#pragma unroll
      for (int nf = 0; nf < 3; ++nf) {
        const int c = c0 + wc * 48 + nf * 16 + (lane & 15);
        const int nb = n0 + wr * 128 + m * 16 + r4;
        ushort4 u;
        u.x = f2bf(acc[m][nf][0]);
        u.y = f2bf(acc[m][nf][1]);
        u.z = f2bf(acc[m][nf][2]);
        u.w = f2bf(acc[m][nf][3]);
        *reinterpret_cast<ushort4*>(&Hb[(size_t)c * N_ + nb]) = u;
      }
    }
  }
#undef STGA
#undef STGB
#undef RD_B
#undef RD_A8
#undef MFMA24
#undef MIDBAR
#undef ENDBAR
#undef WAITV
}

// ---------------------------------------------------------------------------
// Workspace layout (bytes):
//   adjb : [0, 67108864)                 8*2048*2048 bf16
//   G1   : [67108864, 92274688)          8*768*2048 bf16   (reused as Ht)
//   G2   : [92274688, 117440512)         8*768*2048 bf16
// ---------------------------------------------------------------------------
extern "C" void kernel_launch(void* const* d_in, const int* in_sizes, int n_in,
                              void* d_out, int out_size, void* d_ws, size_t ws_size,
                              hipStream_t stream) {
  const float* x   = (const float*)d_in[0];
  const float* adj = (const float*)d_in[1];
  const float* W0  = (const float*)d_in[2];
  const float* b0  = (const float*)d_in[3];
  const float* W1  = (const float*)d_in[4];
  const float* b1  = (const float*)d_in[5];
  const float* W2  = (const float*)d_in[6];
  const float* b2  = (const float*)d_in[7];
  float* out = (float*)d_out;

  char* ws = (char*)d_ws;
  unsigned short* adjb = (unsigned short*)ws;
  unsigned short* G1   = (unsigned short*)(ws + 67108864);
  unsigned short* G2   = (unsigned short*)(ws + 92274688);
  unsigned short* Ht   = G1;  // G1 dead after diffusion pass 1 -> reuse

  hipFuncSetAttribute((const void*)gemm8_k,
                      hipFuncAttributeMaxDynamicSharedMemorySize, 131072);

  // 1) adj -> bf16
  hipLaunchKernelGGL(convert_adj_k, dim3((B_ * N_ * N_ / 4) / 256), dim3(256), 0, stream,
                     adj, adjb);

  // 2) p=0: out channels [0,64) directly
  hipLaunchKernelGGL(p0_k, dim3(NT / 64, B_), dim3(256), 0, stream,
                     x, W0, b0, out);

  // 3) p=1,2 feature transforms -> G1, G2 (bf16, [c][m] layout)
  hipLaunchKernelGGL(p12_k, dim3(N_ / 16, B_), dim3(256), 0, stream,
                     x, W1, b1, W2, b2, G1, G2);

  // 4) diffusion p=1: out[64:128] = leaky(adj @ G1)
  hipLaunchKernelGGL(gemm8_k, dim3(256), dim3(512), 131072, stream,
                     adjb, G1, out, (unsigned short*)nullptr, 0, 64);

  // 5) diffusion p=2 hop 1: Ht = bf16(adj @ G2)
  hipLaunchKernelGGL(gemm8_k, dim3(256), dim3(512), 131072, stream,
                     adjb, G2, out, Ht, 1, 0);

  // 6) diffusion p=2 hop 2: out[128:192] = leaky(adj @ Ht)
  hipLaunchKernelGGL(gemm8_k, dim3(256), dim3(512), 131072, stream,
                     adjb, Ht, out, (unsigned short*)nullptr, 0, 128);
}